// Round 1
// baseline (159.499 us; speedup 1.0000x reference)
//
#include <hip/hip_runtime.h>
#include <math.h>

#define NB 2
#define NR 16384
#define NRAY (NB*NR)   // 32768 rays
#define NS 48
#define NC 32
#define ND 64

// d_ws layout (12 bytes used): [0]=global min bits (uint), [1]=global max bits (uint), [2]=var sum (float)

__global__ void init_ws_kernel(unsigned int* ws) {
    ws[0] = 0x7f7fffffu;   // FLT_MAX bits (depths are positive)
    ws[1] = 0u;
    ((float*)ws)[2] = 0.0f;
}

__global__ void minmax_kernel(const float* __restrict__ depths, unsigned int* __restrict__ ws) {
    int ray = blockIdx.x * blockDim.x + threadIdx.x;   // 32768 threads
    // depths are sorted along S, so per-ray min/max are the endpoints
    float mn = depths[(size_t)ray * NS];
    float mx = depths[(size_t)ray * NS + (NS - 1)];
#pragma unroll
    for (int off = 32; off > 0; off >>= 1) {
        mn = fminf(mn, __shfl_xor(mn, off));
        mx = fmaxf(mx, __shfl_xor(mx, off));
    }
    if ((threadIdx.x & 63) == 0) {
        atomicMin(&ws[0], __float_as_uint(mn));   // uint order == float order for positive floats
        atomicMax(&ws[1], __float_as_uint(mx));
    }
}

__global__ __launch_bounds__(256) void march_kernel(
    const float* __restrict__ colors, const float* __restrict__ densities,
    const float* __restrict__ depths, const float* __restrict__ dinos,
    float* __restrict__ out, const unsigned int* __restrict__ ws_mm,
    float* __restrict__ ws_var)
{
    const int wid  = threadIdx.x >> 6;
    const int lane = threadIdx.x & 63;
    const int ray  = blockIdx.x * 4 + wid;

    __shared__ float v_sh[4][NS];
    __shared__ float var_sh[4];

    const float* dep = depths    + (size_t)ray * NS;
    const float* den = densities + (size_t)ray * NS;

    float d_i = (lane < NS) ? dep[lane] : 0.f;
    float n_i = (lane < NS) ? den[lane] : 0.f;
    float d_n = __shfl_down(d_i, 1);
    float n_n = __shfl_down(n_i, 1);

    const bool act = (lane < NS - 1);             // 47 intervals
    float delta = d_n - d_i;
    float dm    = 0.5f * (d_i + d_n);             // depths_mid
    float x     = 0.5f * (n_i + n_n) - 1.0f;      // densities_mid - 1
    float sp    = fmaxf(x, 0.f) + log1pf(expf(-fabsf(x)));   // stable softplus
    float alpha = act ? (1.f - expf(-sp * delta)) : 0.f;
    float f     = act ? (1.f - alpha + 1e-10f) : 1.f;

    // inclusive prefix product (Kogge-Stone) over 64 lanes
    float incl = f;
#pragma unroll
    for (int off = 1; off < 64; off <<= 1) {
        float o = __shfl_up(incl, off);
        if (lane >= off) incl *= o;
    }
    float T = __shfl_up(incl, 1);
    if (lane == 0) T = 1.f;
    float w  = alpha * T;                         // lanes >= 47 have w == 0
    float bg = __shfl(incl, 45);                  // T_46 = prod_{j<=45} f_j

    // butterfly reductions: W = sum w, M = sum w*dm (all lanes get result)
    float W = w, M = w * dm;
#pragma unroll
    for (int off = 32; off > 0; off >>= 1) {
        W += __shfl_xor(W, off);
        M += __shfl_xor(M, off);
    }
    // exact two-pass variance numerator: sum w*(dm - M)^2
    float dv = dm - M;
    float vn = w * dv * dv;
#pragma unroll
    for (int off = 32; off > 0; off >>= 1) vn += __shfl_xor(vn, off);

    // coefficients v_j = 0.5*(w_{j-1} + w_j), j = 0..47 (w_{-1} = w_47 = 0)
    float wprev = __shfl_up(w, 1);
    if (lane == 0) wprev = 0.f;
    float v = 0.5f * (wprev + w);
    if (lane < NS) v_sh[wid][lane] = v;           // same-wave LDS RAW: no barrier needed

    // output chunk bases (return order, flat)
    float* out_rgb = out;
    float* out_dep = out + (size_t)NRAY * NC;
    float* out_w   = out + (size_t)NRAY * (NC + 1);
    float* out_bg  = out + (size_t)NRAY * (NC + 1 + (NS - 1));
    float* out_din = out + (size_t)NRAY * (NC + 2 + (NS - 1));
    float* out_wt  = out + (size_t)NRAY * (NC + 2 + (NS - 1) + ND);

    if (act) out_w[(size_t)ray * (NS - 1) + lane] = w;

    if (lane == 0) {
        float cd = M / W;
        if (cd != cd) cd = INFINITY;              // nan_to_num(nan=inf)
        float gmin = __uint_as_float(ws_mm[0]);
        float gmax = __uint_as_float(ws_mm[1]);
        cd = fminf(fmaxf(cd, gmin), gmax);        // clip (inf -> gmax)
        out_dep[ray] = cd;
        out_bg[ray]  = bg;
        out_wt[ray]  = W;
        var_sh[wid]  = vn / (W + 1e-6f);
    }

    // composite_rgb: lanes (h = lane>>5, c = lane&31); each iter = 256B coalesced wave read
    {
        const int h = lane >> 5, c = lane & 31;
        const float* cp = colors + (size_t)ray * (NS * NC) + c;
        float acc = 0.f;
#pragma unroll
        for (int t = 0; t < NS / 2; ++t) {
            int j = h + 2 * t;
            acc += v_sh[wid][j] * cp[(size_t)j * NC];
        }
        acc += __shfl_xor(acc, 32);
        if (lane < NC) out_rgb[(size_t)ray * NC + lane] = 2.f * acc - 1.f;
    }

    // composite_dino: lane = channel, 48 coalesced 256B wave reads
    {
        const float* dp = dinos + (size_t)ray * (NS * ND) + lane;
        float acc = 0.f;
#pragma unroll
        for (int j = 0; j < NS; ++j) acc += v_sh[wid][j] * dp[(size_t)j * ND];
        out_din[(size_t)ray * ND + lane] = 2.f * (acc + 1.f - W) - 1.f;
    }

    __syncthreads();
    if (threadIdx.x == 0) {
        atomicAdd(ws_var, var_sh[0] + var_sh[1] + var_sh[2] + var_sh[3]);
    }
}

__global__ void finalize_kernel(const float* __restrict__ ws, float* __restrict__ out) {
    out[(size_t)NRAY * 146] = ws[2] * (1.0f / (float)NRAY);   // mean over B*R rays
}

extern "C" void kernel_launch(void* const* d_in, const int* in_sizes, int n_in,
                              void* d_out, int out_size, void* d_ws, size_t ws_size,
                              hipStream_t stream) {
    const float* colors    = (const float*)d_in[0];
    const float* densities = (const float*)d_in[1];
    const float* depths    = (const float*)d_in[2];
    const float* dinos     = (const float*)d_in[3];
    float* out = (float*)d_out;
    unsigned int* ws = (unsigned int*)d_ws;

    hipLaunchKernelGGL(init_ws_kernel, dim3(1), dim3(1), 0, stream, ws);
    hipLaunchKernelGGL(minmax_kernel, dim3(NRAY / 256), dim3(256), 0, stream, depths, ws);
    hipLaunchKernelGGL(march_kernel, dim3(NRAY / 4), dim3(256), 0, stream,
                       colors, densities, depths, dinos, out, ws, (float*)ws + 2);
    hipLaunchKernelGGL(finalize_kernel, dim3(1), dim3(1), 0, stream, (const float*)ws, out);
}